// Round 4
// baseline (562.512 us; speedup 1.0000x reference)
//
#include <hip/hip_runtime.h>
#include <hip/hip_bf16.h>

// ChromaticTransportEvaluator — round 4.
// R3 post-mortem: gemm_div was ~9.5us/dispatch vs 0.8us of MFMA work ->
// latency-bound at 1 wave/SIMD (1024 waves total). Fix: 4-way k-split,
// 16x16 output tile per block, grid (64,32)=2048 blocks = 8 waves/SIMD.
//
// mfma_f32_16x16x32_bf16 layouts (guide §3, m89-verified):
//   A[m][k]: m = lane&15, k = (lane>>4)*8 + reg   (8 contiguous k -> 16B load)
//   B[k][n]: n = lane&15, k = (lane>>4)*8 + reg   (mirror)
//   C/D:     col = lane&15, row = (lane>>4)*4 + reg

#define LAB_STRIDE 786432         // 4*3*256*256 floats per image-set

typedef __attribute__((ext_vector_type(8))) short short8;
typedef __attribute__((ext_vector_type(4))) float floatx4;

__device__ __forceinline__ float hw_exp2(float x) { return __builtin_amdgcn_exp2f(x); }
__device__ __forceinline__ float hw_log2(float x) { return __builtin_amdgcn_logf(x); }

__device__ __forceinline__ unsigned enc_f(float f) {
    unsigned u = __float_as_uint(f);
    return (u & 0x80000000u) ? ~u : (u | 0x80000000u);
}
__device__ __forceinline__ float dec_f(unsigned k) {
    unsigned u = (k & 0x80000000u) ? (k ^ 0x80000000u) : ~k;
    return __uint_as_float(u);
}

__device__ __forceinline__ float s2lin(float x) {
    x = fminf(fmaxf(x, 0.f), 1.f);
    return (x <= 0.04045f) ? (x * (1.f / 12.92f))
                           : hw_exp2(2.4f * hw_log2((x + 0.055f) * (1.f / 1.055f)));
}

__device__ __forceinline__ float cbrt_fast(float l) {
    return hw_exp2(0.33333333333f * hw_log2(fmaxf(l, 1e-12f)));
}

__device__ __forceinline__ void lohi_img(const unsigned* mm, int img,
                                         float lo[3], float hi[3]) {
    for (int c = 0; c < 3; ++c) {
        float mn = dec_f(mm[img * 6 + c * 2 + 0]);
        float mx = dec_f(mm[img * 6 + c * 2 + 1]);
        float l = mn - 0.01f, h = mx + 0.01f;
        if (h - l < 1e-4f) { l -= 0.05f; h += 0.05f; }
        lo[c] = l; hi[c] = h;
    }
}

// bf16 RNE split helpers
__device__ __forceinline__ unsigned bf16_rne(float f) {
    unsigned u = __float_as_uint(f);
    return (u + 0x7FFFu + ((u >> 16) & 1u)) >> 16;
}
__device__ __forceinline__ float bf16_to_f(unsigned short b) {
    return __uint_as_float(((unsigned)b) << 16);
}

__global__ void init_kernel(unsigned* mm, float* emd) {
    int t = threadIdx.x;              // 1024 threads
    if (t < 12) mm[t] = (t & 1) ? 0u : 0xFFFFFFFFu;
    emd[t] = 0.f;
}

// 1024 blocks x 256 threads, 2 px/thread. Blocks 0..511 -> ref, 512..1023 -> tgt.
__global__ __launch_bounds__(256) void oklab_minmax_kernel(
        const float* __restrict__ ref, const float* __restrict__ tgt,
        float* __restrict__ lab, unsigned* __restrict__ mm) {
    int blk = blockIdx.x;
    int img = blk >> 9;
    const float* src = img ? tgt : ref;
    float* dst = lab + img * LAB_STRIDE;

    __shared__ unsigned smin[3], smax[3];
    if (threadIdx.x < 3) { smin[threadIdx.x] = 0xFFFFFFFFu; smax[threadIdx.x] = 0u; }
    __syncthreads();

    float fmn[3] = {3.4e38f, 3.4e38f, 3.4e38f};
    float fmx[3] = {-3.4e38f, -3.4e38f, -3.4e38f};

    int base = (blk & 511) * 512;
    for (int k = 0; k < 2; ++k) {
        int px = base + k * 256 + threadIdx.x;   // 0..262143
        int bi = px >> 16;
        int rem = px & 65535;
        float r = s2lin(src[(bi * 3 + 0) * 65536 + rem]);
        float g = s2lin(src[(bi * 3 + 1) * 65536 + rem]);
        float b = s2lin(src[(bi * 3 + 2) * 65536 + rem]);
        float l0 = fmaxf(0.4122214708f * r + 0.5363325363f * g + 0.0514459929f * b, 0.f);
        float l1 = fmaxf(0.2119034982f * r + 0.6806995451f * g + 0.1073969566f * b, 0.f);
        float l2 = fmaxf(0.0883024619f * r + 0.2817188376f * g + 0.6299787005f * b, 0.f);
        float g0 = (l0 > 0.f) ? cbrt_fast(l0) : 0.f;
        float g1 = (l1 > 0.f) ? cbrt_fast(l1) : 0.f;
        float g2 = (l2 > 0.f) ? cbrt_fast(l2) : 0.f;
        float L = 0.2104542553f * g0 + 0.793617785f * g1 - 0.0040720468f * g2;
        float A = 1.9779984951f * g0 - 2.428592205f * g1 + 0.4505937099f * g2;
        float Bv = 0.0259040371f * g0 + 0.7827717662f * g1 - 0.808675766f * g2;
        dst[(bi * 3 + 0) * 65536 + rem] = L;
        dst[(bi * 3 + 1) * 65536 + rem] = A;
        dst[(bi * 3 + 2) * 65536 + rem] = Bv;
        fmn[0] = fminf(fmn[0], L); fmx[0] = fmaxf(fmx[0], L);
        fmn[1] = fminf(fmn[1], A); fmx[1] = fmaxf(fmx[1], A);
        fmn[2] = fminf(fmn[2], Bv); fmx[2] = fmaxf(fmx[2], Bv);
    }
    for (int c = 0; c < 3; ++c) {
        atomicMin(&smin[c], enc_f(fmn[c]));
        atomicMax(&smax[c], enc_f(fmx[c]));
    }
    __syncthreads();
    if (threadIdx.x < 3) {
        atomicMin(&mm[img * 6 + threadIdx.x * 2 + 0], smin[threadIdx.x]);
        atomicMax(&mm[img * 6 + threadIdx.x * 2 + 1], smax[threadIdx.x]);
    }
}

// Pack K=exp(-cost/0.1) and Kc=K*cost into hi/lo bf16, B-fragment order.
// grid (32 jtiles, 16 kchunks) x 64 threads. Element for (jt,kc,lane,reg):
//   k = kc*32 + (lane>>4)*8 + reg, n = jt*16 + (lane&15)
//   stored at [((jt*16+kc)*64 + lane)*8 + reg]
__global__ __launch_bounds__(64) void pack_k_kernel(
        const unsigned* __restrict__ mm,
        short* __restrict__ kmh, short* __restrict__ kml,
        short* __restrict__ kch, short* __restrict__ kcl) {
    float lor[3], hir[3], lot[3], hit[3];
    lohi_img(mm, 0, lor, hir);
    lohi_img(mm, 1, lot, hit);
    float cen[3][8];
    for (int c = 0; c < 3; ++c)
        for (int k = 0; k < 8; ++k) {
            float t = (k + 0.5f) * 0.125f;
            cen[c][k] = 0.5f * ((lor[c] + (hir[c] - lor[c]) * t)
                              + (lot[c] + (hit[c] - lot[c]) * t));
        }
    int jt = blockIdx.x, kc = blockIdx.y;
    int lane = threadIdx.x;
    int n = jt * 16 + (lane & 15);
    int kb = kc * 32 + (lane >> 4) * 8;
    float n0 = cen[0][n >> 6], n1 = cen[1][(n >> 3) & 7], n2 = cen[2][n & 7];
    short8 vmh, vml, vch, vcl;
    #pragma unroll
    for (int r = 0; r < 8; ++r) {
        int k = kb + r;
        float d0 = cen[0][k >> 6] - n0;
        float d1 = cen[1][(k >> 3) & 7] - n1;
        float d2 = cen[2][k & 7] - n2;
        float dd = d0 * d0 + d1 * d1 + d2 * d2;
        float cost = (dd > 0.f) ? __fsqrt_rn(dd) : 0.f;
        // exp(-10*cost) = exp2(-10*cost*log2(e))
        float kv = hw_exp2(-cost * 14.426950408889634f);
        float cv = kv * cost;
        unsigned h = bf16_rne(kv);
        float hf = bf16_to_f((unsigned short)h);
        unsigned l = bf16_rne(kv - hf);
        vmh[r] = (short)h; vml[r] = (short)l;
        h = bf16_rne(cv);
        hf = bf16_to_f((unsigned short)h);
        l = bf16_rne(cv - hf);
        vch[r] = (short)h; vcl[r] = (short)l;
    }
    int base = ((jt * 16 + kc) * 64 + lane) * 8;
    *(short8*)(kmh + base) = vmh;
    *(short8*)(kml + base) = vml;
    *(short8*)(kch + base) = vch;
    *(short8*)(kcl + base) = vcl;
}

// 2048 blocks: img = blk>>10, patch = blk&1023. 256 threads = 256 pixels.
__global__ __launch_bounds__(256) void hist_kernel(
        const float* __restrict__ lab, const unsigned* __restrict__ mm,
        float* __restrict__ hr, float* __restrict__ ht,
        short* __restrict__ uh, short* __restrict__ ul) {
    int blk = blockIdx.x;
    int img = blk >> 10;
    int p = blk & 1023;
    float lo[3], hi[3];
    lohi_img(mm, img, lo, hi);
    float cen[3][8];
    for (int c = 0; c < 3; ++c)
        for (int k = 0; k < 8; ++k)
            cen[c][k] = lo[c] + (hi[c] - lo[c]) * ((k + 0.5f) * 0.125f);

    __shared__ unsigned hcnt[512];
    hcnt[threadIdx.x] = 0u;
    hcnt[threadIdx.x + 256] = 0u;
    __syncthreads();

    int b = p >> 8, ph = (p >> 4) & 15, pw = p & 15;
    int y = threadIdx.x >> 4, x = threadIdx.x & 15;
    int rem = (ph * 16 + y) * 256 + (pw * 16 + x);
    const float* lb = lab + img * LAB_STRIDE;
    int kidx[3];
    for (int c = 0; c < 3; ++c) {
        float vv = lb[(b * 3 + c) * 65536 + rem];
        int best = 0; float bd = 3.4e38f;
        for (int k = 0; k < 8; ++k) {
            float d = vv - cen[c][k];
            float dd = d * d;
            if (dd < bd) { bd = dd; best = k; }
        }
        kidx[c] = best;
    }
    atomicAdd(&hcnt[kidx[0] * 64 + kidx[1] * 8 + kidx[2]], 1u);
    __syncthreads();

    float* dst = img ? ht : hr;
    dst[p * 512 + threadIdx.x] = (float)hcnt[threadIdx.x] * (1.f / 256.f);
    dst[p * 512 + threadIdx.x + 256] = (float)hcnt[threadIdx.x + 256] * (1.f / 256.f);
    if (!img) {   // u0 = ones (split: hi=1.0 bf16, lo=0)
        uh[p * 512 + threadIdx.x] = (short)0x3F80;
        uh[p * 512 + threadIdx.x + 256] = (short)0x3F80;
        ul[p * 512 + threadIdx.x] = 0;
        ul[p * 512 + threadIdx.x + 256] = 0;
    }
}

// dst[p,j] = hist[p,j] / (sum_i src[p,i] K[i,j] + 1e-6), output split hi/lo bf16.
// grid (64 p-tiles of 16, 32 j-tiles of 16), 256 threads (4 waves), 4-way
// k-split (each wave reduces k-range of 128), LDS combine. 2048 blocks ->
// 8 blocks/CU -> 8 waves/SIMD for latency hiding.
__global__ __launch_bounds__(256, 8) void gemm_div_kernel(
        const short* __restrict__ ah_g, const short* __restrict__ al_g,
        const short* __restrict__ bh_g, const short* __restrict__ bl_g,
        const float* __restrict__ hist,
        short* __restrict__ dh_g, short* __restrict__ dl_g) {
    __shared__ float red[1024];
    int tid = threadIdx.x;
    int wave = tid >> 6, lane = tid & 63;
    int pt = blockIdx.x, jt = blockIdx.y;
    int arow = (pt * 16 + (lane & 15)) * 512 + wave * 128 + ((lane >> 4) << 3);
    floatx4 acc = {0.f, 0.f, 0.f, 0.f};
    #pragma unroll
    for (int kc = 0; kc < 4; ++kc) {
        int aoff = arow + kc * 32;
        short8 ah = *(const short8*)(ah_g + aoff);
        short8 al = *(const short8*)(al_g + aoff);
        int boff = ((jt * 16 + wave * 4 + kc) * 64 + lane) * 8;
        short8 bh = *(const short8*)(bh_g + boff);
        short8 bl = *(const short8*)(bl_g + boff);
        acc = __builtin_amdgcn_mfma_f32_16x16x32_bf16(ah, bh, acc, 0, 0, 0);
        acc = __builtin_amdgcn_mfma_f32_16x16x32_bf16(ah, bl, acc, 0, 0, 0);
        acc = __builtin_amdgcn_mfma_f32_16x16x32_bf16(al, bh, acc, 0, 0, 0);
    }
    *(floatx4*)&red[wave * 256 + lane * 4] = acc;
    __syncthreads();
    float s = red[tid] + red[tid + 256] + red[tid + 512] + red[tid + 768];
    int lane2 = tid >> 2, r = tid & 3;
    int row = pt * 16 + ((lane2 >> 4) << 2) + r;
    int col = jt * 16 + (lane2 & 15);
    int idx = row * 512 + col;
    float d = hist[idx] / (s + 1e-6f);
    unsigned h = bf16_rne(d);
    dh_g[idx] = (short)h;
    dl_g[idx] = (short)bf16_rne(d - bf16_to_f((unsigned short)h));
}

// emd[p] += sum_j (sum_i u[p,i] Kc[i,j]) * v[p,j] — same k-split GEMM,
// reduce epilogue (LDS per-row sums, one global atomic per row).
__global__ __launch_bounds__(256, 8) void emd_gemm_kernel(
        const short* __restrict__ ah_g, const short* __restrict__ al_g,
        const short* __restrict__ bh_g, const short* __restrict__ bl_g,
        const short* __restrict__ vh_g, const short* __restrict__ vl_g,
        float* __restrict__ emd) {
    __shared__ float red[1024];
    __shared__ float es[16];
    int tid = threadIdx.x;
    int wave = tid >> 6, lane = tid & 63;
    int pt = blockIdx.x, jt = blockIdx.y;
    int arow = (pt * 16 + (lane & 15)) * 512 + wave * 128 + ((lane >> 4) << 3);
    floatx4 acc = {0.f, 0.f, 0.f, 0.f};
    #pragma unroll
    for (int kc = 0; kc < 4; ++kc) {
        int aoff = arow + kc * 32;
        short8 ah = *(const short8*)(ah_g + aoff);
        short8 al = *(const short8*)(al_g + aoff);
        int boff = ((jt * 16 + wave * 4 + kc) * 64 + lane) * 8;
        short8 bh = *(const short8*)(bh_g + boff);
        short8 bl = *(const short8*)(bl_g + boff);
        acc = __builtin_amdgcn_mfma_f32_16x16x32_bf16(ah, bh, acc, 0, 0, 0);
        acc = __builtin_amdgcn_mfma_f32_16x16x32_bf16(ah, bl, acc, 0, 0, 0);
        acc = __builtin_amdgcn_mfma_f32_16x16x32_bf16(al, bh, acc, 0, 0, 0);
    }
    *(floatx4*)&red[wave * 256 + lane * 4] = acc;
    if (tid < 16) es[tid] = 0.f;
    __syncthreads();
    float s = red[tid] + red[tid + 256] + red[tid + 512] + red[tid + 768];
    int lane2 = tid >> 2, r = tid & 3;
    int rloc = ((lane2 >> 4) << 2) + r;
    int row = pt * 16 + rloc;
    int col = jt * 16 + (lane2 & 15);
    int idx = row * 512 + col;
    float vv = bf16_to_f((unsigned short)vh_g[idx]) + bf16_to_f((unsigned short)vl_g[idx]);
    atomicAdd(&es[rloc], s * vv);
    __syncthreads();
    if (tid < 16) atomicAdd(&emd[pt * 16 + tid], es[tid]);
}

// (4,1,16,16) -> (4,1,256,256), half-pixel bilinear, edge clamp, nan_to_num
__global__ __launch_bounds__(256) void upsample_kernel(
        const float* __restrict__ emd, float* __restrict__ out) {
    int idx = blockIdx.x * 256 + threadIdx.x;   // 0..262143
    int b = idx >> 16;
    int rem = idx & 65535;
    int y = rem >> 8, x = rem & 255;
    float sy = (y + 0.5f) * 0.0625f - 0.5f;
    float sx = (x + 0.5f) * 0.0625f - 0.5f;
    float fy0 = floorf(sy), fx0 = floorf(sx);
    float fy = sy - fy0, fx = sx - fx0;
    int y0 = (int)fy0, x0 = (int)fx0;
    int y0c = min(max(y0, 0), 15), y1c = min(max(y0 + 1, 0), 15);
    int x0c = min(max(x0, 0), 15), x1c = min(max(x0 + 1, 0), 15);
    const float* e = emd + b * 256;
    float v00 = e[y0c * 16 + x0c], v01 = e[y0c * 16 + x1c];
    float v10 = e[y1c * 16 + x0c], v11 = e[y1c * 16 + x1c];
    if (!__builtin_isfinite(v00)) v00 = 0.f;
    if (!__builtin_isfinite(v01)) v01 = 0.f;
    if (!__builtin_isfinite(v10)) v10 = 0.f;
    if (!__builtin_isfinite(v11)) v11 = 0.f;
    out[idx] = (1.f - fy) * ((1.f - fx) * v00 + fx * v01)
             + fy * ((1.f - fx) * v10 + fx * v11);
}

extern "C" void kernel_launch(void* const* d_in, const int* in_sizes, int n_in,
                              void* d_out, int out_size, void* d_ws, size_t ws_size,
                              hipStream_t stream) {
    const float* ref = (const float*)d_in[0];
    const float* tgt = (const float*)d_in[1];
    float* out = (float*)d_out;

    float* lab = (float*)d_ws;                       // 1572864 f32
    unsigned* mm = (unsigned*)(lab + 2 * LAB_STRIDE); // 16 u32
    float* hr = (float*)(mm + 16);                    // 524288 f32
    float* ht = hr + 524288;                          // 524288 f32
    float* emd = ht + 524288;                         // 1024 f32
    short* uh = (short*)(emd + 1024);                 // 524288 bf16
    short* ul = uh + 524288;
    short* vh = ul + 524288;
    short* vl = vh + 524288;
    short* kmh = vl + 524288;                         // 262144 bf16
    short* kml = kmh + 262144;
    short* kch = kml + 262144;
    short* kcl = kch + 262144;

    init_kernel<<<1, 1024, 0, stream>>>(mm, emd);
    oklab_minmax_kernel<<<1024, 256, 0, stream>>>(ref, tgt, lab, mm);
    pack_k_kernel<<<dim3(32, 16), 64, 0, stream>>>(mm, kmh, kml, kch, kcl);
    hist_kernel<<<2048, 256, 0, stream>>>(lab, mm, hr, ht, uh, ul);

    for (int it = 0; it < 20; ++it) {
        gemm_div_kernel<<<dim3(64, 32), 256, 0, stream>>>(uh, ul, kmh, kml, ht, vh, vl);
        gemm_div_kernel<<<dim3(64, 32), 256, 0, stream>>>(vh, vl, kmh, kml, hr, uh, ul);
    }
    emd_gemm_kernel<<<dim3(64, 32), 256, 0, stream>>>(uh, ul, kch, kcl, vh, vl, emd);
    upsample_kernel<<<1024, 256, 0, stream>>>(emd, out);
}